// Round 2
// baseline (170.173 us; speedup 1.0000x reference)
//
#include <hip/hip_runtime.h>
#include <cstdint>

#define B_SZ 8192
#define D_SZ 512
#define K_SZ 2048
#define EPSV 1e-8f
// 1/TEMP
#define INV_T 2.0f

typedef short short8 __attribute__((ext_vector_type(8)));
typedef float floatx4 __attribute__((ext_vector_type(4)));

// fp32 -> bf16 round-to-nearest-even (inputs are finite random normals; no NaN path)
__device__ __forceinline__ unsigned short f2bf(float f) {
    unsigned int u = __float_as_uint(f);
    u += 0x7FFFu + ((u >> 16) & 1u);
    return (unsigned short)(u >> 16);
}

// async global->LDS, 16B per lane. LDS dest must be wave-uniform base + lane*16.
__device__ __forceinline__ void async_cp16(const void* g, void* l) {
    typedef __attribute__((address_space(1))) unsigned int gds_t;
    typedef __attribute__((address_space(3))) unsigned int lds_t;
    __builtin_amdgcn_global_load_lds((gds_t*)(unsigned long long)g, (lds_t*)l, 16, 0, 0);
}

// ---------------------------------------------------------------------------
// Kernel 1 (merged prep+gather):
//  blocks [0,2048):  per-row norms of z_i/z_j, positive logit, z_i -> bf16 A
//  blocks [2048,3072): gather 2K=4096 rows (c_k, c_k+1) of z_j -> bf16 G + norms
// One wave per row in both halves.
// ---------------------------------------------------------------------------
__global__ __launch_bounds__(256) void k_prep(
    const float* __restrict__ zi, const float* __restrict__ zj,
    const int* __restrict__ perm,
    float* __restrict__ ni_arr, float* __restrict__ pos_arr,
    unsigned short* __restrict__ A,
    float* __restrict__ njc, unsigned short* __restrict__ G)
{
    int w = threadIdx.x >> 6, l = threadIdx.x & 63;
    if (blockIdx.x < 2048) {
        int row = blockIdx.x * 4 + w;
        const float4* zi4 = (const float4*)(zi + (size_t)row * D_SZ);
        const float4* zj4 = (const float4*)(zj + (size_t)row * D_SZ);
        float4 a0 = zi4[2 * l], a1 = zi4[2 * l + 1];
        float4 b0 = zj4[2 * l], b1 = zj4[2 * l + 1];
        float si = a0.x * a0.x + a0.y * a0.y + a0.z * a0.z + a0.w * a0.w
                 + a1.x * a1.x + a1.y * a1.y + a1.z * a1.z + a1.w * a1.w;
        float sj = b0.x * b0.x + b0.y * b0.y + b0.z * b0.z + b0.w * b0.w
                 + b1.x * b1.x + b1.y * b1.y + b1.z * b1.z + b1.w * b1.w;
        float dd = a0.x * b0.x + a0.y * b0.y + a0.z * b0.z + a0.w * b0.w
                 + a1.x * b1.x + a1.y * b1.y + a1.z * b1.z + a1.w * b1.w;
        for (int m = 1; m < 64; m <<= 1) {
            si += __shfl_xor(si, m);
            sj += __shfl_xor(sj, m);
            dd += __shfl_xor(dd, m);
        }
        if (l == 0) {
            float ni = sqrtf(si), nj = sqrtf(sj);
            ni_arr[row] = ni;
            pos_arr[row] = dd / fmaxf(ni * nj, EPSV) * INV_T;
        }
        union { unsigned short u[8]; uint4 v; } pk;
        pk.u[0] = f2bf(a0.x); pk.u[1] = f2bf(a0.y); pk.u[2] = f2bf(a0.z); pk.u[3] = f2bf(a0.w);
        pk.u[4] = f2bf(a1.x); pk.u[5] = f2bf(a1.y); pk.u[6] = f2bf(a1.z); pk.u[7] = f2bf(a1.w);
        *(uint4*)(A + (size_t)row * D_SZ + l * 8) = pk.v;
    } else {
        int g = (blockIdx.x - 2048) * 4 + w;        // 0..4095
        int c = perm[g >> 1] + (g & 1);             // actual z_j row
        const float4* src = (const float4*)(zj + (size_t)c * D_SZ);
        float4 a0 = src[2 * l], a1 = src[2 * l + 1];
        float s = a0.x * a0.x + a0.y * a0.y + a0.z * a0.z + a0.w * a0.w
                + a1.x * a1.x + a1.y * a1.y + a1.z * a1.z + a1.w * a1.w;
        for (int m = 1; m < 64; m <<= 1) s += __shfl_xor(s, m);
        if (l == 0) njc[g] = sqrtf(s);
        union { unsigned short u[8]; uint4 v; } pk;
        pk.u[0] = f2bf(a0.x); pk.u[1] = f2bf(a0.y); pk.u[2] = f2bf(a0.z); pk.u[3] = f2bf(a0.w);
        pk.u[4] = f2bf(a1.x); pk.u[5] = f2bf(a1.y); pk.u[6] = f2bf(a1.z); pk.u[7] = f2bf(a1.w);
        *(uint4*)(G + (size_t)g * D_SZ + l * 8) = pk.v;
    }
}

// ---------------------------------------------------------------------------
// Kernel 2: bf16 MFMA GEMM S = A (8192x512) . G^T (512x4096), fused epilogue.
// 128x128 tile, BK=64, 256 threads (4 waves, 2x2), 16x16x32 MFMA.
// DOUBLE-BUFFERED LDS: prefetch of k-block d+1 is issued right after the
// top-of-loop barrier, so the loop-back barrier drains a load that has had
// the entire compute phase in flight (one barrier per iteration).
// XOR-swizzled chunk layout keeps ds_read_b128 conflict-free.
// ---------------------------------------------------------------------------
__global__ __launch_bounds__(256) void k_gemm(
    const unsigned short* __restrict__ A,   // [8192][512] bf16
    const unsigned short* __restrict__ G,   // [4096][512] bf16
    const int* __restrict__ perm,           // [2048]
    const float* __restrict__ ni_arr,       // [8192]
    const float* __restrict__ njc,          // [4096]
    const float* __restrict__ pos_arr,      // [8192]
    float* __restrict__ ws_pe, float* __restrict__ ws_pc)  // [8192][64]
{
    __shared__ unsigned short Asl[2][128 * 64];
    __shared__ unsigned short Gsl[2][128 * 64];
    const int tid = threadIdx.x;
    const int l = tid & 63, w = tid >> 6;
    const int wm = w >> 1, wn = w & 1;
    const int q = l >> 4, ln = l & 15;
    const int rowBase = blockIdx.y * 128;
    const int colBase = blockIdx.x * 128;

    // per-thread staging offsets (elements); source advances 64 elems per dblk
    size_t aOff[4], gOff[4];
    int ldsOff[4];
    #pragma unroll
    for (int it = 0; it < 4; ++it) {
        int fc = it * 256 + tid;            // chunk 0..1023 (8 bf16 each)
        int r = fc >> 3;
        int scc = (fc & 7) ^ (r & 7);       // XOR swizzle source chunk
        aOff[it] = (size_t)(rowBase + r) * D_SZ + scc * 8;
        gOff[it] = (size_t)(colBase + r) * D_SZ + scc * 8;
        ldsOff[it] = fc * 8;
    }

    floatx4 acc[4][4] = {};

    // prologue: stage k-block 0 into buffer 0
    #pragma unroll
    for (int it = 0; it < 4; ++it) {
        async_cp16(A + aOff[it], &Asl[0][ldsOff[it]]);
        async_cp16(G + gOff[it], &Gsl[0][ldsOff[it]]);
    }

    for (int dblk = 0; dblk < 8; ++dblk) {
        const int cur = dblk & 1, nxt = cur ^ 1;
        __syncthreads();                    // staged data for `cur` is ready
        if (dblk < 7) {
            #pragma unroll
            for (int it = 0; it < 4; ++it) {
                async_cp16(A + aOff[it] + (size_t)(dblk + 1) * 64, &Asl[nxt][ldsOff[it]]);
                async_cp16(G + gOff[it] + (size_t)(dblk + 1) * 64, &Gsl[nxt][ldsOff[it]]);
            }
        }
        #pragma unroll
        for (int kc = 0; kc < 2; ++kc) {
            short8 af[4], bfr[4];
            #pragma unroll
            for (int t = 0; t < 4; ++t) {
                int ar = wm * 64 + t * 16 + ln;
                int ac = (kc * 4 + q) ^ (ar & 7);
                af[t] = *(const short8*)&Asl[cur][ar * 64 + ac * 8];
                int br = wn * 64 + t * 16 + ln;
                int bc = (kc * 4 + q) ^ (br & 7);
                bfr[t] = *(const short8*)&Gsl[cur][br * 64 + bc * 8];
            }
            #pragma unroll
            for (int tm = 0; tm < 4; ++tm)
                #pragma unroll
                for (int tn = 0; tn < 4; ++tn)
                    acc[tm][tn] = __builtin_amdgcn_mfma_f32_16x16x32_bf16(
                        af[tm], bfr[tn], acc[tm][tn], 0, 0, 0);
        }
    }

    // ---- fused epilogue ----
    // C/D layout: col = ln, row = q*4 + reg
    const int cb = blockIdx.x * 2 + wn;     // 64-col chunk index, 0..63
    float njv[4]; int cv[4], shv[4];
    #pragma unroll
    for (int tn = 0; tn < 4; ++tn) {
        int g = colBase + wn * 64 + tn * 16 + ln;
        cv[tn] = perm[g >> 1];
        shv[tn] = g & 1;
        njv[tn] = njc[g];
    }
    #pragma unroll
    for (int tm = 0; tm < 4; ++tm) {
        int row0 = rowBase + wm * 64 + tm * 16 + q * 4;
        #pragma unroll
        for (int r = 0; r < 4; ++r) {
            int row = row0 + r;
            float niv = ni_arr[row];
            float pv = pos_arr[row];
            float pe = 0.f, pc = 0.f;
            #pragma unroll
            for (int tn = 0; tn < 4; ++tn) {
                float v = acc[tm][tn][r];
                float logit = v * INV_T / fmaxf(niv * njv[tn], EPSV);
                // row uses column c+1 iff c >= row; our gathered col is c+shv
                bool use = ((cv[tn] >= row) ? 1 : 0) == shv[tn];
                if (use) {
                    pe += __expf(logit);
                    pc += (logit > pv) ? 1.f : 0.f;
                }
            }
            // reduce over the 16 lanes sharing this row (masks < 16 stay in q-group)
            #pragma unroll
            for (int m = 1; m < 16; m <<= 1) {
                pe += __shfl_xor(pe, m);
                pc += __shfl_xor(pc, m);
            }
            if (ln == 0) {
                ws_pe[(size_t)row * 64 + cb] = pe;
                ws_pc[(size_t)row * 64 + cb] = pc;
            }
        }
    }
}

// ---------------------------------------------------------------------------
// Kernel 3: per-row finalize + global reduction into d_out[3].
// Wave-per-row: 128 blocks x 256 threads, 64 rows per block (16 rows/wave).
// ---------------------------------------------------------------------------
__global__ __launch_bounds__(256) void k_final(
    const float* __restrict__ ws_pe, const float* __restrict__ ws_pc,
    const float* __restrict__ pos_arr, float* __restrict__ out)
{
    int w = threadIdx.x >> 6, l = threadIdx.x & 63;
    float lsum = 0.f, a1sum = 0.f, a5sum = 0.f;
    #pragma unroll 4
    for (int j = 0; j < 16; ++j) {
        int row = blockIdx.x * 64 + j * 4 + w;
        float pe = ws_pe[(size_t)row * 64 + l];
        float pc = ws_pc[(size_t)row * 64 + l];
        for (int m = 1; m < 64; m <<= 1) {
            pe += __shfl_xor(pe, m);
            pc += __shfl_xor(pc, m);
        }
        if (l == 0) {
            float pos = pos_arr[row];
            lsum += logf(__expf(pos) + pe) - pos;   // logsumexp - pos (logits bounded)
            a1sum += (pc < 0.5f) ? 1.f : 0.f;       // no neg strictly > pos
            a5sum += (pc < 4.5f) ? 1.f : 0.f;       // at most 4 negs strictly > pos
        }
    }
    __shared__ float red[3][4];
    if (l == 0) { red[0][w] = lsum; red[1][w] = a1sum; red[2][w] = a5sum; }
    __syncthreads();
    if (threadIdx.x == 0) {
        float L = red[0][0] + red[0][1] + red[0][2] + red[0][3];
        float A1 = red[1][0] + red[1][1] + red[1][2] + red[1][3];
        float A5 = red[2][0] + red[2][1] + red[2][2] + red[2][3];
        atomicAdd(&out[0], L / (float)B_SZ);
        atomicAdd(&out[1], A1 * (100.f / (float)B_SZ));
        atomicAdd(&out[2], A5 * (100.f / (float)B_SZ));
    }
}

// ---------------------------------------------------------------------------
extern "C" void kernel_launch(void* const* d_in, const int* in_sizes, int n_in,
                              void* d_out, int out_size, void* d_ws, size_t ws_size,
                              hipStream_t stream)
{
    const float* zi = (const float*)d_in[0];
    const float* zj = (const float*)d_in[1];
    const int* perm = (const int*)d_in[2];
    float* out = (float*)d_out;

    // workspace layout (all 16B aligned)
    char* p = (char*)d_ws;
    unsigned short* A = (unsigned short*)p;  p += (size_t)B_SZ * D_SZ * 2;      // 8 MB
    unsigned short* G = (unsigned short*)p;  p += (size_t)2 * K_SZ * D_SZ * 2;  // 4 MB
    float* ni_arr = (float*)p;               p += (size_t)B_SZ * 4;
    float* pos_arr = (float*)p;              p += (size_t)B_SZ * 4;
    float* njc = (float*)p;                  p += (size_t)2 * K_SZ * 4;
    float* ws_pe = (float*)p;                p += (size_t)B_SZ * 64 * 4;        // 2 MB
    float* ws_pc = (float*)p;                p += (size_t)B_SZ * 64 * 4;        // 2 MB

    hipMemsetAsync(d_out, 0, 3 * sizeof(float), stream);

    k_prep<<<2048 + 1024, 256, 0, stream>>>(zi, zj, perm, ni_arr, pos_arr, A, njc, G);
    k_gemm<<<dim3(32, 64), 256, 0, stream>>>(A, G, perm, ni_arr, njc, pos_arr,
                                             ws_pe, ws_pc);
    k_final<<<128, 256, 0, stream>>>(ws_pe, ws_pc, pos_arr, out);
}

// Round 3
// 165.583 us; speedup vs baseline: 1.0277x; 1.0277x over previous
//
#include <hip/hip_runtime.h>
#include <cstdint>

#define B_SZ 8192
#define D_SZ 512
#define K_SZ 2048
#define EPSV 1e-8f
// 1/TEMP
#define INV_T 2.0f

typedef short short8 __attribute__((ext_vector_type(8)));
typedef float floatx4 __attribute__((ext_vector_type(4)));

// fp32 -> bf16 round-to-nearest-even (inputs are finite random normals; no NaN path)
__device__ __forceinline__ unsigned short f2bf(float f) {
    unsigned int u = __float_as_uint(f);
    u += 0x7FFFu + ((u >> 16) & 1u);
    return (unsigned short)(u >> 16);
}

// async global->LDS, 16B per lane. LDS dest must be wave-uniform base + lane*16.
__device__ __forceinline__ void async_cp16(const void* g, void* l) {
    typedef __attribute__((address_space(1))) unsigned int gds_t;
    typedef __attribute__((address_space(3))) unsigned int lds_t;
    __builtin_amdgcn_global_load_lds((gds_t*)(unsigned long long)g, (lds_t*)l, 16, 0, 0);
}

// ---------------------------------------------------------------------------
// Kernel 1 (merged prep+gather):
//  blocks [0,2048):  per-row norms of z_i/z_j, positive logit, z_i -> bf16 A
//  blocks [2048,3072): gather 2K=4096 rows (c_k, c_k+1) of z_j -> bf16 G + norms
// One wave per row in both halves.
// ---------------------------------------------------------------------------
__global__ __launch_bounds__(256) void k_prep(
    const float* __restrict__ zi, const float* __restrict__ zj,
    const int* __restrict__ perm,
    float* __restrict__ ni_arr, float* __restrict__ pos_arr,
    unsigned short* __restrict__ A,
    float* __restrict__ njc, unsigned short* __restrict__ G)
{
    int w = threadIdx.x >> 6, l = threadIdx.x & 63;
    if (blockIdx.x < 2048) {
        int row = blockIdx.x * 4 + w;
        const float4* zi4 = (const float4*)(zi + (size_t)row * D_SZ);
        const float4* zj4 = (const float4*)(zj + (size_t)row * D_SZ);
        float4 a0 = zi4[2 * l], a1 = zi4[2 * l + 1];
        float4 b0 = zj4[2 * l], b1 = zj4[2 * l + 1];
        float si = a0.x * a0.x + a0.y * a0.y + a0.z * a0.z + a0.w * a0.w
                 + a1.x * a1.x + a1.y * a1.y + a1.z * a1.z + a1.w * a1.w;
        float sj = b0.x * b0.x + b0.y * b0.y + b0.z * b0.z + b0.w * b0.w
                 + b1.x * b1.x + b1.y * b1.y + b1.z * b1.z + b1.w * b1.w;
        float dd = a0.x * b0.x + a0.y * b0.y + a0.z * b0.z + a0.w * b0.w
                 + a1.x * b1.x + a1.y * b1.y + a1.z * b1.z + a1.w * b1.w;
        for (int m = 1; m < 64; m <<= 1) {
            si += __shfl_xor(si, m);
            sj += __shfl_xor(sj, m);
            dd += __shfl_xor(dd, m);
        }
        if (l == 0) {
            float ni = sqrtf(si), nj = sqrtf(sj);
            ni_arr[row] = ni;
            pos_arr[row] = dd / fmaxf(ni * nj, EPSV) * INV_T;
        }
        union { unsigned short u[8]; uint4 v; } pk;
        pk.u[0] = f2bf(a0.x); pk.u[1] = f2bf(a0.y); pk.u[2] = f2bf(a0.z); pk.u[3] = f2bf(a0.w);
        pk.u[4] = f2bf(a1.x); pk.u[5] = f2bf(a1.y); pk.u[6] = f2bf(a1.z); pk.u[7] = f2bf(a1.w);
        *(uint4*)(A + (size_t)row * D_SZ + l * 8) = pk.v;
    } else {
        int g = (blockIdx.x - 2048) * 4 + w;        // 0..4095
        int c = perm[g >> 1] + (g & 1);             // actual z_j row
        const float4* src = (const float4*)(zj + (size_t)c * D_SZ);
        float4 a0 = src[2 * l], a1 = src[2 * l + 1];
        float s = a0.x * a0.x + a0.y * a0.y + a0.z * a0.z + a0.w * a0.w
                + a1.x * a1.x + a1.y * a1.y + a1.z * a1.z + a1.w * a1.w;
        for (int m = 1; m < 64; m <<= 1) s += __shfl_xor(s, m);
        if (l == 0) njc[g] = sqrtf(s);
        union { unsigned short u[8]; uint4 v; } pk;
        pk.u[0] = f2bf(a0.x); pk.u[1] = f2bf(a0.y); pk.u[2] = f2bf(a0.z); pk.u[3] = f2bf(a0.w);
        pk.u[4] = f2bf(a1.x); pk.u[5] = f2bf(a1.y); pk.u[6] = f2bf(a1.z); pk.u[7] = f2bf(a1.w);
        *(uint4*)(G + (size_t)g * D_SZ + l * 8) = pk.v;
    }
}

// ---------------------------------------------------------------------------
// Kernel 2: bf16 MFMA GEMM S = A (8192x512) . G^T (512x4096), fused epilogue.
// 128x128 tile, BK=32, 256 threads (4 waves, 2x2), 16x16x32 MFMA.
// DOUBLE-BUFFERED LDS (32 KB total -> 5 blocks/CU occupancy): prefetch of
// k-block d+1 issued right after the top-of-loop barrier; loop-back barrier
// drains a load that had the whole compute phase in flight.
// XOR swizzle: LDS slot s of row r holds source chunk s ^ ((r^(r>>2))&3);
// a wave's frag read covers each 1 KB stripe as a bijection -> conflict-free.
// ---------------------------------------------------------------------------
__global__ __launch_bounds__(256) void k_gemm(
    const unsigned short* __restrict__ A,   // [8192][512] bf16
    const unsigned short* __restrict__ G,   // [4096][512] bf16
    const int* __restrict__ perm,           // [2048]
    const float* __restrict__ ni_arr,       // [8192]
    const float* __restrict__ njc,          // [4096]
    const float* __restrict__ pos_arr,      // [8192]
    float* __restrict__ ws_pe, float* __restrict__ ws_pc)  // [8192][64]
{
    __shared__ unsigned short Asl[2][128 * 32];
    __shared__ unsigned short Gsl[2][128 * 32];
    const int tid = threadIdx.x;
    const int l = tid & 63, w = tid >> 6;
    const int wm = w >> 1, wn = w & 1;
    const int q = l >> 4, ln = l & 15;
    const int rowBase = blockIdx.y * 128;
    const int colBase = blockIdx.x * 128;

    // per-thread staging offsets (elements); source advances 32 elems per dblk
    size_t aOff[2], gOff[2];
    int ldsOff[2];
    #pragma unroll
    for (int it = 0; it < 2; ++it) {
        int fc = it * 256 + tid;            // chunk 0..511 (8 bf16 each)
        int r = fc >> 2, s = fc & 3;
        int scc = s ^ ((r ^ (r >> 2)) & 3); // XOR swizzle source chunk
        aOff[it] = (size_t)(rowBase + r) * D_SZ + scc * 8;
        gOff[it] = (size_t)(colBase + r) * D_SZ + scc * 8;
        ldsOff[it] = fc * 8;
    }

    floatx4 acc[4][4] = {};

    // prologue: stage k-block 0 into buffer 0
    #pragma unroll
    for (int it = 0; it < 2; ++it) {
        async_cp16(A + aOff[it], &Asl[0][ldsOff[it]]);
        async_cp16(G + gOff[it], &Gsl[0][ldsOff[it]]);
    }

    for (int dblk = 0; dblk < 16; ++dblk) {
        const int cur = dblk & 1, nxt = cur ^ 1;
        __syncthreads();                    // staged data for `cur` is ready
        if (dblk < 15) {
            #pragma unroll
            for (int it = 0; it < 2; ++it) {
                async_cp16(A + aOff[it] + (size_t)(dblk + 1) * 32, &Asl[nxt][ldsOff[it]]);
                async_cp16(G + gOff[it] + (size_t)(dblk + 1) * 32, &Gsl[nxt][ldsOff[it]]);
            }
        }
        short8 af[4], bfr[4];
        #pragma unroll
        for (int t = 0; t < 4; ++t) {
            int ar = wm * 64 + t * 16 + ln;
            int as = q ^ ((ar ^ (ar >> 2)) & 3);
            af[t] = *(const short8*)&Asl[cur][ar * 32 + as * 8];
            int br = wn * 64 + t * 16 + ln;
            int bs = q ^ ((br ^ (br >> 2)) & 3);
            bfr[t] = *(const short8*)&Gsl[cur][br * 32 + bs * 8];
        }
        #pragma unroll
        for (int tm = 0; tm < 4; ++tm)
            #pragma unroll
            for (int tn = 0; tn < 4; ++tn)
                acc[tm][tn] = __builtin_amdgcn_mfma_f32_16x16x32_bf16(
                    af[tm], bfr[tn], acc[tm][tn], 0, 0, 0);
    }

    // ---- fused epilogue ----
    // C/D layout: col = ln, row = q*4 + reg
    const int cb = blockIdx.x * 2 + wn;     // 64-col chunk index, 0..63
    float njv[4]; int cv[4], shv[4];
    #pragma unroll
    for (int tn = 0; tn < 4; ++tn) {
        int g = colBase + wn * 64 + tn * 16 + ln;
        cv[tn] = perm[g >> 1];
        shv[tn] = g & 1;
        njv[tn] = njc[g];
    }
    #pragma unroll
    for (int tm = 0; tm < 4; ++tm) {
        int row0 = rowBase + wm * 64 + tm * 16 + q * 4;
        #pragma unroll
        for (int r = 0; r < 4; ++r) {
            int row = row0 + r;
            float niv = ni_arr[row];
            float pv = pos_arr[row];
            float pe = 0.f, pc = 0.f;
            #pragma unroll
            for (int tn = 0; tn < 4; ++tn) {
                float v = acc[tm][tn][r];
                float logit = v * INV_T / fmaxf(niv * njv[tn], EPSV);
                // row uses column c+1 iff c >= row; our gathered col is c+shv
                bool use = ((cv[tn] >= row) ? 1 : 0) == shv[tn];
                if (use) {
                    pe += __expf(logit);
                    pc += (logit > pv) ? 1.f : 0.f;
                }
            }
            // reduce over the 16 lanes sharing this row (masks < 16 stay in q-group)
            #pragma unroll
            for (int m = 1; m < 16; m <<= 1) {
                pe += __shfl_xor(pe, m);
                pc += __shfl_xor(pc, m);
            }
            if (ln == 0) {
                ws_pe[(size_t)row * 64 + cb] = pe;
                ws_pc[(size_t)row * 64 + cb] = pc;
            }
        }
    }
}

// ---------------------------------------------------------------------------
// Kernel 3: per-row finalize + global reduction into d_out[3].
// Wave-per-row: 128 blocks x 256 threads, 64 rows per block (16 rows/wave).
// ---------------------------------------------------------------------------
__global__ __launch_bounds__(256) void k_final(
    const float* __restrict__ ws_pe, const float* __restrict__ ws_pc,
    const float* __restrict__ pos_arr, float* __restrict__ out)
{
    int w = threadIdx.x >> 6, l = threadIdx.x & 63;
    float lsum = 0.f, a1sum = 0.f, a5sum = 0.f;
    #pragma unroll 4
    for (int j = 0; j < 16; ++j) {
        int row = blockIdx.x * 64 + j * 4 + w;
        float pe = ws_pe[(size_t)row * 64 + l];
        float pc = ws_pc[(size_t)row * 64 + l];
        for (int m = 1; m < 64; m <<= 1) {
            pe += __shfl_xor(pe, m);
            pc += __shfl_xor(pc, m);
        }
        if (l == 0) {
            float pos = pos_arr[row];
            lsum += logf(__expf(pos) + pe) - pos;   // logsumexp - pos (logits bounded)
            a1sum += (pc < 0.5f) ? 1.f : 0.f;       // no neg strictly > pos
            a5sum += (pc < 4.5f) ? 1.f : 0.f;       // at most 4 negs strictly > pos
        }
    }
    __shared__ float red[3][4];
    if (l == 0) { red[0][w] = lsum; red[1][w] = a1sum; red[2][w] = a5sum; }
    __syncthreads();
    if (threadIdx.x == 0) {
        float L = red[0][0] + red[0][1] + red[0][2] + red[0][3];
        float A1 = red[1][0] + red[1][1] + red[1][2] + red[1][3];
        float A5 = red[2][0] + red[2][1] + red[2][2] + red[2][3];
        atomicAdd(&out[0], L / (float)B_SZ);
        atomicAdd(&out[1], A1 * (100.f / (float)B_SZ));
        atomicAdd(&out[2], A5 * (100.f / (float)B_SZ));
    }
}

// ---------------------------------------------------------------------------
extern "C" void kernel_launch(void* const* d_in, const int* in_sizes, int n_in,
                              void* d_out, int out_size, void* d_ws, size_t ws_size,
                              hipStream_t stream)
{
    const float* zi = (const float*)d_in[0];
    const float* zj = (const float*)d_in[1];
    const int* perm = (const int*)d_in[2];
    float* out = (float*)d_out;

    // workspace layout (all 16B aligned)
    char* p = (char*)d_ws;
    unsigned short* A = (unsigned short*)p;  p += (size_t)B_SZ * D_SZ * 2;      // 8 MB
    unsigned short* G = (unsigned short*)p;  p += (size_t)2 * K_SZ * D_SZ * 2;  // 4 MB
    float* ni_arr = (float*)p;               p += (size_t)B_SZ * 4;
    float* pos_arr = (float*)p;              p += (size_t)B_SZ * 4;
    float* njc = (float*)p;                  p += (size_t)2 * K_SZ * 4;
    float* ws_pe = (float*)p;                p += (size_t)B_SZ * 64 * 4;        // 2 MB
    float* ws_pc = (float*)p;                p += (size_t)B_SZ * 64 * 4;        // 2 MB

    hipMemsetAsync(d_out, 0, 3 * sizeof(float), stream);

    k_prep<<<2048 + 1024, 256, 0, stream>>>(zi, zj, perm, ni_arr, pos_arr, A, njc, G);
    k_gemm<<<dim3(32, 64), 256, 0, stream>>>(A, G, perm, ni_arr, njc, pos_arr,
                                             ws_pe, ws_pc);
    k_final<<<128, 256, 0, stream>>>(ws_pe, ws_pc, pos_arr, out);
}